// Round 6
// baseline (246.292 us; speedup 1.0000x reference)
//
#include <hip/hip_runtime.h>
#include <math.h>

typedef float f32x4 __attribute__((ext_vector_type(4)));
typedef int   v4i   __attribute__((ext_vector_type(4)));
typedef int   v8i   __attribute__((ext_vector_type(8)));

// ---------- helpers ----------
__device__ __forceinline__ void g2l16(const void* g, void* l) {
    // async global->LDS, 16B per lane; LDS dest = wave-uniform base + lane*16
    __builtin_amdgcn_global_load_lds(
        (__attribute__((address_space(1))) void*)g,
        (__attribute__((address_space(3))) void*)l,
        16, 0, 0);
}

__device__ __forceinline__ int pk8(float a, float b, int old) {
    return __builtin_amdgcn_cvt_pk_fp8_f32(a, b, old, 0);
}
__device__ __forceinline__ int pk8h(float a, float b, int old) {
    return __builtin_amdgcn_cvt_pk_fp8_f32(a, b, old, 1);
}

// ---------- quant prep: stage 1 — per-block absmax partials ----------
__global__ void wprep1(const float* __restrict__ W1, const float* __restrict__ W2,
                       const float* __restrict__ W3, float* __restrict__ pmax) {
    int blk = blockIdx.x;
    const float* w; int n, b, nb;
    if (blk < 128)      { w = W1; n = 524288;  b = blk;       nb = 128; }
    else if (blk < 256) { w = W2; n = 1048576; b = blk - 128; nb = 128; }
    else                { w = W3; n = 131072;  b = blk - 256; nb = 32;  }
    float m = 0.f;
    for (int i = b * 256 + threadIdx.x; i < n; i += nb * 256)
        m = fmaxf(m, fabsf(w[i]));
    #pragma unroll
    for (int off = 32; off; off >>= 1)
        m = fmaxf(m, __shfl_down(m, off));
    __shared__ float sm[4];
    int lane = threadIdx.x & 63, wv = threadIdx.x >> 6;
    if (lane == 0) sm[wv] = m;
    __syncthreads();
    if (threadIdx.x == 0)
        pmax[blockIdx.x] = fmaxf(fmaxf(sm[0], sm[1]), fmaxf(sm[2], sm[3]));
}

// ---------- stage 2: reduce partials -> scales; quantize biases ----------
__global__ void wprep2(const float* __restrict__ pmax,
                       const float* __restrict__ b1, const float* __restrict__ b2,
                       const float* __restrict__ b3,
                       float* __restrict__ scales,
                       float* __restrict__ b1q, float* __restrict__ b2q, float* __restrict__ b3q) {
    __shared__ float sred[3][4];
    __shared__ float ssc[3];
    int tid = threadIdx.x, lane = tid & 63, wv = tid >> 6;
    float m0 = (tid < 128) ? pmax[tid] : 0.f;
    float m1 = (tid < 128) ? pmax[128 + tid] : 0.f;
    float m2 = (tid < 32)  ? pmax[256 + tid] : 0.f;
    #pragma unroll
    for (int off = 32; off; off >>= 1) {
        m0 = fmaxf(m0, __shfl_down(m0, off));
        m1 = fmaxf(m1, __shfl_down(m1, off));
        m2 = fmaxf(m2, __shfl_down(m2, off));
    }
    if (lane == 0) { sred[0][wv] = m0; sred[1][wv] = m1; sred[2][wv] = m2; }
    __syncthreads();
    if (tid < 3) {
        float mm = fmaxf(fmaxf(sred[tid][0], sred[tid][1]), fmaxf(sred[tid][2], sred[tid][3]));
        float s = mm / 127.0f;
        scales[tid] = s; ssc[tid] = s;
    }
    __syncthreads();
    const float s_in = (float)(1.0 / 12000.0);
    float sb1 = s_in * ssc[0];
    float sb2 = sb1 * ssc[1];
    float sb3 = sb2 * ssc[2];
    for (int i = tid; i < 1024; i += 256) {
        b1q[i] = fminf(fmaxf(rintf(b1[i] / sb1), -128.f), 127.f) * sb1;
        b2q[i] = fminf(fmaxf(rintf(b2[i] / sb2), -128.f), 127.f) * sb2;
    }
    if (tid < 128) b3q[tid] = fminf(fmaxf(rintf(b3[tid] / sb3), -128.f), 127.f) * sb3;
}

// ---------- quantize all weights -> fp8 of (q * ws * 2^10) ----------
__global__ void quant_w_all(const float* __restrict__ W1, const float* __restrict__ W2,
                            const float* __restrict__ W3,
                            unsigned char* __restrict__ W1s, unsigned char* __restrict__ W2s,
                            unsigned char* __restrict__ W3s,
                            const float* __restrict__ scales) {
    int b = blockIdx.x;
    const float* w; unsigned char* o; float s; int base;
    if (b < 256)      { w = W1; o = W1s; s = scales[0]; base = b * 2048; }
    else if (b < 768) { w = W2; o = W2s; s = scales[1]; base = (b - 256) * 2048; }
    else              { w = W3; o = W3s; s = scales[2]; base = (b - 768) * 2048; }
    int i = base + threadIdx.x * 8;
    float4 a = *(const float4*)(w + i);
    float4 c = *(const float4*)(w + i + 4);
    #define QW(x) fminf(fmaxf(fminf(fmaxf(rintf((x) / s), -127.f), 127.f) * s * 1024.f, -448.f), 448.f)
    int lo = pk8(QW(a.x), QW(a.y), 0); lo = pk8h(QW(a.z), QW(a.w), lo);
    int hi = pk8(QW(c.x), QW(c.y), 0); hi = pk8h(QW(c.z), QW(c.w), hi);
    #undef QW
    *(int2*)(o + i) = make_int2(lo, hi);
}

// ---------- obs f32 -> fp8 ----------
__global__ void cvt_fp8(const float* __restrict__ in, unsigned char* __restrict__ out) {
    int i = (blockIdx.x * blockDim.x + threadIdx.x) * 8;
    float4 a = *(const float4*)(in + i);
    float4 c = *(const float4*)(in + i + 4);
    int lo = pk8(a.x, a.y, 0); lo = pk8h(a.z, a.w, lo);
    int hi = pk8(c.x, c.y, 0); hi = pk8h(c.z, c.w, hi);
    *(int2*)(out + i) = make_int2(lo, hi);
}

// ---------- MX-fp8 GEMM: out_fp8 = fp8( relu(A@Wt^T * descale + bias) * osc ) ----------
// Block 256(M)x128(N), BK=128 B. A staged via global_load_lds (xor-chunk swizzle,
// conflict-free); B (L2-resident weights) loaded global->reg, flatmm-style, issued
// before A staging so the barrier's vmcnt(0) drain covers their latency.
// Epilogue routes f32 through LDS with +4-float row padding (132) -> 2-way writes,
// minimum-phase b128 reads; packs fp8 and stores dwordx4.
template <int LGX>
__global__ __launch_bounds__(256, 2)
void gemm8(const unsigned char* __restrict__ A,   // [M,K] fp8
           const unsigned char* __restrict__ Wt,  // [N,K] fp8 (pre-scaled 2^10)
           const float* __restrict__ bias,        // [N] f32
           unsigned char* __restrict__ out,       // [M,N] fp8
           float descale, float osc, int N, int K) {
    __shared__ char smem[33792];   // max(lA 32 KB, fS 64*132*4 B)
    char* lA = smem;               // 256x128 B
    const int tid  = threadIdx.x;
    const int wv   = tid >> 6, lane = tid & 63;
    const int wr   = wv >> 1,  wc   = wv & 1;     // wave: 128 rows x 64 cols
    const int l15  = lane & 15, l4  = lane >> 4;
    const int lid  = blockIdx.y * gridDim.x + blockIdx.x;
    const int xcd  = lid & 7;
    const int s    = lid >> 3;
    const int mblk = (s >> LGX) * 8 + xcd;
    const int nblk = s & ((1 << LGX) - 1);
    const size_t rowA0 = (size_t)mblk * 256;
    const size_t rowB0 = (size_t)nblk * 128;
    const unsigned char* Ab = A  + rowA0 * K;
    const unsigned char* Bb = Wt + rowB0 * K;
    const int qsw = ((tid & 7) ^ ((tid >> 3) & 7)) * 16;   // swizzled src chunk offset
    const int srow = tid >> 3;                             // 0..31

    f32x4 acc[8][4];
    #pragma unroll
    for (int i = 0; i < 8; ++i)
        #pragma unroll
        for (int j = 0; j < 4; ++j)
            acc[i][j] = f32x4{0.f, 0.f, 0.f, 0.f};

    const int p0 = ((l4 * 2) ^ (l15 & 7)) * 16;       // LDS chunk of k-lo 16B
    const int p1 = ((l4 * 2 + 1) ^ (l15 & 7)) * 16;   // LDS chunk of k-hi 16B

    for (int k0 = 0; k0 < K; k0 += 128) {
        // B: global -> regs (lane: row l15 of j-tile, k = l4*32 .. +31)
        union { v8i v; v4i h[2]; } bfr[4];
        #pragma unroll
        for (int j = 0; j < 4; ++j) {
            const unsigned char* bp = Bb + (size_t)(wc * 64 + j * 16 + l15) * K + k0 + l4 * 32;
            bfr[j].h[0] = *(const v4i*)bp;
            bfr[j].h[1] = *(const v4i*)(bp + 16);
        }
        #pragma unroll
        for (int c = 0; c < 8; ++c)
            g2l16(Ab + (size_t)(c * 32 + srow) * K + k0 + qsw, lA + c * 4096 + tid * 16);
        __syncthreads();
        #pragma unroll
        for (int i = 0; i < 8; ++i) {
            const char* ar = lA + (wr * 128 + i * 16 + l15) * 128;
            union { v8i v; v4i h[2]; } af;
            af.h[0] = *(const v4i*)(ar + p0);
            af.h[1] = *(const v4i*)(ar + p1);
            #pragma unroll
            for (int j = 0; j < 4; ++j)
                acc[i][j] = __builtin_amdgcn_mfma_scale_f32_16x16x128_f8f6f4(
                    af.v, bfr[j].v, acc[i][j], 0, 0, 0, 0x7F7F7F7F, 0, 0x7F7F7F7F);
        }
        __syncthreads();
    }

    // Epilogue: 4 bands of 64 rows via padded LDS (132 floats/row)
    float* fS = (float*)smem;
    const int rr = tid >> 2;                  // 0..63
    const int cb = (tid & 3) * 32;
    float bvj[4];
    #pragma unroll
    for (int j = 0; j < 4; ++j) bvj[j] = bias[rowB0 + wc * 64 + j * 16 + l15];
    #pragma unroll
    for (int p = 0; p < 4; ++p) {
        __syncthreads();
        if (wr == (p >> 1)) {
            const int ib = (p & 1) * 4;
            #pragma unroll
            for (int ii = 0; ii < 4; ++ii) {
                #pragma unroll
                for (int j = 0; j < 4; ++j) {
                    const int col = wc * 64 + j * 16 + l15;
                    #pragma unroll
                    for (int r = 0; r < 4; ++r) {
                        const int lrow = ii * 16 + l4 * 4 + r;
                        fS[lrow * 132 + col] = fmaxf(acc[ib + ii][j][r] * descale + bvj[j], 0.f);
                    }
                }
            }
        }
        __syncthreads();
        const size_t grow = rowA0 + p * 64 + rr;
        const float* src = fS + rr * 132 + cb;
        #pragma unroll
        for (int h = 0; h < 2; ++h) {
            v4i d;
            #pragma unroll
            for (int m = 0; m < 4; ++m) {
                float a0 = fminf(src[h * 16 + m * 4 + 0] * osc, 448.f);
                float a1 = fminf(src[h * 16 + m * 4 + 1] * osc, 448.f);
                float a2 = fminf(src[h * 16 + m * 4 + 2] * osc, 448.f);
                float a3 = fminf(src[h * 16 + m * 4 + 3] * osc, 448.f);
                d[m] = pk8h(a2, a3, pk8(a0, a1, 0));
            }
            *(v4i*)(out + grow * (size_t)N + rowB0 + cb + h * 16) = d;
        }
    }
}

// ---------- GEMM3 + finale fused (fp8 inputs): 64 rows/block, B global->reg ----------
__global__ __launch_bounds__(256)
void gemm3_fused(const unsigned char* __restrict__ A,   // h2 [B,1024] fp8
                 const unsigned char* __restrict__ Wt,  // W3 [128,1024] fp8
                 const float* __restrict__ bias,        // [128]
                 const float* __restrict__ eps,         // [B,64]
                 float* __restrict__ act_out, float* __restrict__ logp_out,
                 float descale, int K) {
    __shared__ char smem[32768];
    char* lA = smem;                      // 64x128 B = 8 KB
    float* fmu = (float*)smem;            // epilogue 64x64 f32
    float* fls = (float*)(smem + 16384);
    const int tid  = threadIdx.x;
    const int wv   = tid >> 6, lane = tid & 63;
    const int wr   = wv >> 1,  wc   = wv & 1;     // wave: 32 rows x 64 cols
    const int l15  = lane & 15, l4  = lane >> 4;
    const size_t rowA0 = (size_t)blockIdx.x * 64;
    const unsigned char* Ab = A + rowA0 * K;
    const int qsw = ((tid & 7) ^ ((tid >> 3) & 7)) * 16;
    const int srow = tid >> 3;
    const int p0 = ((l4 * 2) ^ (l15 & 7)) * 16;
    const int p1 = ((l4 * 2 + 1) ^ (l15 & 7)) * 16;

    f32x4 acc[2][4];
    #pragma unroll
    for (int i = 0; i < 2; ++i)
        #pragma unroll
        for (int j = 0; j < 4; ++j)
            acc[i][j] = f32x4{0.f, 0.f, 0.f, 0.f};

    for (int k0 = 0; k0 < K; k0 += 128) {
        union { v8i v; v4i h[2]; } bfr[4];
        #pragma unroll
        for (int j = 0; j < 4; ++j) {
            const unsigned char* bp = Wt + (size_t)(wc * 64 + j * 16 + l15) * K + k0 + l4 * 32;
            bfr[j].h[0] = *(const v4i*)bp;
            bfr[j].h[1] = *(const v4i*)(bp + 16);
        }
        #pragma unroll
        for (int c = 0; c < 2; ++c)
            g2l16(Ab + (size_t)(c * 32 + srow) * K + k0 + qsw, lA + c * 4096 + tid * 16);
        __syncthreads();
        union { v8i v; v4i h[2]; } af[2];
        #pragma unroll
        for (int i = 0; i < 2; ++i) {
            const char* ar = lA + (wr * 32 + i * 16 + l15) * 128;
            af[i].h[0] = *(const v4i*)(ar + p0);
            af[i].h[1] = *(const v4i*)(ar + p1);
        }
        #pragma unroll
        for (int i = 0; i < 2; ++i)
            #pragma unroll
            for (int j = 0; j < 4; ++j)
                acc[i][j] = __builtin_amdgcn_mfma_scale_f32_16x16x128_f8f6f4(
                    af[i].v, bfr[j].v, acc[i][j], 0, 0, 0, 0x7F7F7F7F, 0, 0x7F7F7F7F);
        __syncthreads();
    }

    // Epilogue: cols 0..63 = mu (wc=0), 64..127 = log_std (wc=1); +row rotation in LDS
    {
        float* dst = wc ? fls : fmu;
        #pragma unroll
        for (int i = 0; i < 2; ++i) {
            #pragma unroll
            for (int j = 0; j < 4; ++j) {
                int c = j * 16 + l15;                 // 0..63
                float bv = bias[wc * 64 + c];
                #pragma unroll
                for (int r = 0; r < 4; ++r) {
                    int lr = wr * 32 + i * 16 + l4 * 4 + r;   // 0..63
                    dst[lr * 64 + ((c + lr) & 63)] = acc[i][j][r] * descale + bv;
                }
            }
        }
    }
    __syncthreads();
    {
        int r = tid >> 2;                              // 0..63
        size_t grow = rowA0 + r;
        float lp = 0.f;
        #pragma unroll
        for (int t = 0; t < 16; ++t) {
            int j = (tid & 3) * 16 + t;                // 0..63
            int rot = (j + r) & 63;
            float mu = fmu[r * 64 + rot];
            float ls = fls[r * 64 + rot];
            ls = fminf(fmaxf(ls, -20.f), 2.f);
            float sd = expf(ls);
            float e  = eps[grow * 64 + j];
            float pi = fmaf(sd, e, mu);
            act_out[grow * 64 + j] = tanhf(pi);
            lp += -0.5f * e * e - ls - 0.91893853320467274178f;
            float xn = -2.f * pi;
            float sp = fmaxf(xn, 0.f) + log1pf(expf(-fabsf(xn)));
            lp -= 2.f * (0.69314718055994530942f - pi - sp);
        }
        lp += __shfl_xor(lp, 1);
        lp += __shfl_xor(lp, 2);
        if ((tid & 3) == 0) logp_out[grow] = lp;
    }
}

// ---------- launch ----------
extern "C" void kernel_launch(void* const* d_in, const int* in_sizes, int n_in,
                              void* d_out, int out_size, void* d_ws, size_t ws_size,
                              hipStream_t stream) {
    const float* obs = (const float*)d_in[0];
    const float* eps = (const float*)d_in[1];
    const float* W1  = (const float*)d_in[2];
    const float* b1  = (const float*)d_in[3];
    const float* W2  = (const float*)d_in[4];
    const float* b2  = (const float*)d_in[5];
    const float* W3  = (const float*)d_in[6];
    const float* b3  = (const float*)d_in[7];
    const int B = 32768, OBS = 512, H1 = 1024, H2 = 1024;

    char* ws = (char*)d_ws;
    unsigned char* x8  = (unsigned char*)(ws);               // 16 MB [B*512]
    unsigned char* h1  = (unsigned char*)(ws + 16777216);    // 32 MB
    unsigned char* h2  = (unsigned char*)(ws + 50331648);    // 32 MB
    unsigned char* W1s = (unsigned char*)(ws + 83886080);    // 512 KB
    unsigned char* W2s = (unsigned char*)(ws + 84410368);    // 1 MB
    unsigned char* W3s = (unsigned char*)(ws + 85458944);    // 128 KB
    float*         b1q = (float*)(ws + 85590016);
    float*         b2q = (float*)(ws + 85594112);
    float*         b3q = (float*)(ws + 85598208);
    float*         scales = (float*)(ws + 85598720);
    float*         pmax   = (float*)(ws + 85599232);

    wprep1<<<288, 256, 0, stream>>>(W1, W2, W3, pmax);
    wprep2<<<1, 256, 0, stream>>>(pmax, b1, b2, b3, scales, b1q, b2q, b3q);
    quant_w_all<<<832, 256, 0, stream>>>(W1, W2, W3, W1s, W2s, W3s, scales);
    cvt_fp8<<<8192, 256, 0, stream>>>(obs, x8);

    // scale bookkeeping (all powers of 2, exact):
    //   W* stored *2^10 ; x stored *1 (s_in^2 folded into descale1)
    //   h1 stored *2^24 ; h2 stored *2^22
    const float desc1 = (float)((1.0 / 12000.0) * (1.0 / 12000.0) / 1024.0);
    const float osc1  = 16777216.f;                   // 2^24
    const float desc2 = 1.0f / 17179869184.f;         // 2^-34
    const float osc2  = 4194304.f;                    // 2^22
    const float desc3 = (float)(1.0 / 4294967296.0);  // 2^-32

    gemm8<3><<<dim3(8, 128), 256, 0, stream>>>(x8, W1s, b1q, h1, desc1, osc1, H1, OBS);
    gemm8<3><<<dim3(8, 128), 256, 0, stream>>>(h1, W2s, b2q, h2, desc2, osc2, H2, H1);

    float* act_out  = (float*)d_out;
    float* logp_out = act_out + (size_t)B * 64;
    gemm3_fused<<<512, 256, 0, stream>>>(h2, W3s, b3q, eps, act_out, logp_out, desc3, H2);
}

// Round 7
// 222.018 us; speedup vs baseline: 1.1093x; 1.1093x over previous
//
#include <hip/hip_runtime.h>
#include <math.h>

typedef float f32x4 __attribute__((ext_vector_type(4)));
typedef int   v4i   __attribute__((ext_vector_type(4)));
typedef int   v8i   __attribute__((ext_vector_type(8)));

// ---------- helpers ----------
__device__ __forceinline__ void g2l16(const void* g, void* l) {
    // async global->LDS, 16B per lane; LDS dest = wave-uniform base + lane*16
    __builtin_amdgcn_global_load_lds(
        (__attribute__((address_space(1))) void*)g,
        (__attribute__((address_space(3))) void*)l,
        16, 0, 0);
}

__device__ __forceinline__ int pk8(float a, float b, int old) {
    return __builtin_amdgcn_cvt_pk_fp8_f32(a, b, old, 0);
}
__device__ __forceinline__ int pk8h(float a, float b, int old) {
    return __builtin_amdgcn_cvt_pk_fp8_f32(a, b, old, 1);
}

// ---------- kernel 1: absmax partials (blocks 0..287) + obs->fp8 (blocks 288..8479) ----------
__global__ void prep_cvt(const float* __restrict__ W1, const float* __restrict__ W2,
                         const float* __restrict__ W3, float* __restrict__ pmax,
                         const float* __restrict__ obs, unsigned char* __restrict__ x8) {
    if (blockIdx.x < 288) {
        int blk = blockIdx.x;
        const float* w; int n, b, nb;
        if (blk < 128)      { w = W1; n = 524288;  b = blk;       nb = 128; }
        else if (blk < 256) { w = W2; n = 1048576; b = blk - 128; nb = 128; }
        else                { w = W3; n = 131072;  b = blk - 256; nb = 32;  }
        float m = 0.f;
        for (int i = b * 256 + threadIdx.x; i < n; i += nb * 256)
            m = fmaxf(m, fabsf(w[i]));
        #pragma unroll
        for (int off = 32; off; off >>= 1)
            m = fmaxf(m, __shfl_down(m, off));
        __shared__ float sm[4];
        int lane = threadIdx.x & 63, wv = threadIdx.x >> 6;
        if (lane == 0) sm[wv] = m;
        __syncthreads();
        if (threadIdx.x == 0)
            pmax[blockIdx.x] = fmaxf(fmaxf(sm[0], sm[1]), fmaxf(sm[2], sm[3]));
    } else {
        int i = ((blockIdx.x - 288) * 256 + threadIdx.x) * 8;
        float4 a = *(const float4*)(obs + i);
        float4 c = *(const float4*)(obs + i + 4);
        int lo = pk8(a.x, a.y, 0); lo = pk8h(a.z, a.w, lo);
        int hi = pk8(c.x, c.y, 0); hi = pk8h(c.z, c.w, hi);
        *(int2*)(x8 + i) = make_int2(lo, hi);
    }
}

// uniform per-block reduction of a pmax segment (all threads return the max)
__device__ __forceinline__ float seg_max(const float* __restrict__ pmax, int base, int cnt,
                                         float* sm) {
    int tid = threadIdx.x, lane = tid & 63, wv = tid >> 6;
    float m = (tid < cnt) ? pmax[base + tid] : 0.f;
    #pragma unroll
    for (int off = 32; off; off >>= 1)
        m = fmaxf(m, __shfl_down(m, off));
    if (lane == 0) sm[wv] = m;
    __syncthreads();
    float r = fmaxf(fmaxf(sm[0], sm[1]), fmaxf(sm[2], sm[3]));
    __syncthreads();
    return r;
}

// ---------- kernel 2: quantize weights -> fp8(q*ws*2^10); block 832 quantizes biases ----------
__global__ void quant_all(const float* __restrict__ W1, const float* __restrict__ W2,
                          const float* __restrict__ W3,
                          const float* __restrict__ b1, const float* __restrict__ b2,
                          const float* __restrict__ b3,
                          unsigned char* __restrict__ W1s, unsigned char* __restrict__ W2s,
                          unsigned char* __restrict__ W3s,
                          float* __restrict__ b1q, float* __restrict__ b2q, float* __restrict__ b3q,
                          const float* __restrict__ pmax) {
    __shared__ float sm[4];
    int b = blockIdx.x, tid = threadIdx.x;
    if (b < 832) {
        const float* w; unsigned char* o; int base, pb, pc;
        if (b < 256)      { w = W1; o = W1s; base = b * 2048;         pb = 0;   pc = 128; }
        else if (b < 768) { w = W2; o = W2s; base = (b - 256) * 2048; pb = 128; pc = 128; }
        else              { w = W3; o = W3s; base = (b - 768) * 2048; pb = 256; pc = 32;  }
        float s = seg_max(pmax, pb, pc, sm) / 127.0f;
        int i = base + tid * 8;
        float4 a = *(const float4*)(w + i);
        float4 c = *(const float4*)(w + i + 4);
        #define QW(x) fminf(fmaxf(fminf(fmaxf(rintf((x) / s), -127.f), 127.f) * s * 1024.f, -448.f), 448.f)
        int lo = pk8(QW(a.x), QW(a.y), 0); lo = pk8h(QW(a.z), QW(a.w), lo);
        int hi = pk8(QW(c.x), QW(c.y), 0); hi = pk8h(QW(c.z), QW(c.w), hi);
        #undef QW
        *(int2*)(o + i) = make_int2(lo, hi);
    } else {
        float ws1 = seg_max(pmax, 0, 128, sm) / 127.0f;
        float ws2 = seg_max(pmax, 128, 128, sm) / 127.0f;
        float ws3 = seg_max(pmax, 256, 32, sm) / 127.0f;
        const float s_in = (float)(1.0 / 12000.0);
        float sb1 = s_in * ws1;
        float sb2 = sb1 * ws2;
        float sb3 = sb2 * ws3;
        for (int i = tid; i < 1024; i += 256) {
            b1q[i] = fminf(fmaxf(rintf(b1[i] / sb1), -128.f), 127.f) * sb1;
            b2q[i] = fminf(fmaxf(rintf(b2[i] / sb2), -128.f), 127.f) * sb2;
        }
        if (tid < 128) b3q[tid] = fminf(fmaxf(rintf(b3[tid] / sb3), -128.f), 127.f) * sb3;
    }
}

// ---------- MX-fp8 GEMM: out_fp8 = fp8( relu(A@Wt^T * descale + bias) * osc ) ----------
// Block 256(M)x128(N), BK=128 B. A and B staged via global_load_lds with xor-chunk
// swizzle (measured conflict-free). Epilogue: padded LDS rows (132 f32), 8-float
// read chunks strided 32 cols -> uniform 2-way banks (free), dwordx2 fp8 stores.
template <int LGX>
__global__ __launch_bounds__(256, 2)
void gemm8(const unsigned char* __restrict__ A,   // [M,K] fp8
           const unsigned char* __restrict__ Wt,  // [N,K] fp8 (pre-scaled 2^10)
           const float* __restrict__ bias,        // [N] f32
           unsigned char* __restrict__ out,       // [M,N] fp8
           float descale, float osc, int N, int K) {
    __shared__ char smem[49152];
    char* lA = smem;            // 256x128 B = 32 KB
    char* lB = smem + 32768;    // 128x128 B = 16 KB
    const int tid  = threadIdx.x;
    const int wv   = tid >> 6, lane = tid & 63;
    const int wr   = wv >> 1,  wc   = wv & 1;     // wave: 128 rows x 64 cols
    const int l15  = lane & 15, l4  = lane >> 4;
    const int lid  = blockIdx.y * gridDim.x + blockIdx.x;
    const int xcd  = lid & 7;
    const int s    = lid >> 3;
    const int mblk = (s >> LGX) * 8 + xcd;
    const int nblk = s & ((1 << LGX) - 1);
    const size_t rowA0 = (size_t)mblk * 256;
    const size_t rowB0 = (size_t)nblk * 128;
    const unsigned char* Ab = A  + rowA0 * K;
    const unsigned char* Bb = Wt + rowB0 * K;
    const int qsw = ((tid & 7) ^ ((tid >> 3) & 7)) * 16;   // swizzled src chunk offset
    const int srow = tid >> 3;                             // 0..31

    f32x4 acc[8][4];
    #pragma unroll
    for (int i = 0; i < 8; ++i)
        #pragma unroll
        for (int j = 0; j < 4; ++j)
            acc[i][j] = f32x4{0.f, 0.f, 0.f, 0.f};

    const int p0 = ((l4 * 2) ^ (l15 & 7)) * 16;       // LDS chunk of k-lo 16B
    const int p1 = ((l4 * 2 + 1) ^ (l15 & 7)) * 16;   // LDS chunk of k-hi 16B

    for (int k0 = 0; k0 < K; k0 += 128) {
        #pragma unroll
        for (int c = 0; c < 8; ++c)
            g2l16(Ab + (size_t)(c * 32 + srow) * K + k0 + qsw, lA + c * 4096 + tid * 16);
        #pragma unroll
        for (int c = 0; c < 4; ++c)
            g2l16(Bb + (size_t)(c * 32 + srow) * K + k0 + qsw, lB + c * 4096 + tid * 16);
        __syncthreads();
        union { v8i v; v4i h[2]; } bfr[4];
        #pragma unroll
        for (int j = 0; j < 4; ++j) {
            const char* br = lB + (wc * 64 + j * 16 + l15) * 128;
            bfr[j].h[0] = *(const v4i*)(br + p0);
            bfr[j].h[1] = *(const v4i*)(br + p1);
        }
        #pragma unroll
        for (int i = 0; i < 8; ++i) {
            const char* ar = lA + (wr * 128 + i * 16 + l15) * 128;
            union { v8i v; v4i h[2]; } af;
            af.h[0] = *(const v4i*)(ar + p0);
            af.h[1] = *(const v4i*)(ar + p1);
            #pragma unroll
            for (int j = 0; j < 4; ++j)
                acc[i][j] = __builtin_amdgcn_mfma_scale_f32_16x16x128_f8f6f4(
                    af.v, bfr[j].v, acc[i][j], 0, 0, 0, 0x7F7F7F7F, 0, 0x7F7F7F7F);
        }
        __syncthreads();
    }

    // Epilogue: 4 bands of 64 rows via padded LDS (132 f32/row)
    float* fS = (float*)smem;
    const int rr = tid >> 2;                  // 0..63
    const int c0 = (tid & 3) * 8;             // 8-float chunks, strided 32 cols
    float bvj[4];
    #pragma unroll
    for (int j = 0; j < 4; ++j) bvj[j] = bias[rowB0 + wc * 64 + j * 16 + l15];
    #pragma unroll
    for (int p = 0; p < 4; ++p) {
        __syncthreads();
        if (wr == (p >> 1)) {
            const int ib = (p & 1) * 4;
            #pragma unroll
            for (int ii = 0; ii < 4; ++ii) {
                #pragma unroll
                for (int j = 0; j < 4; ++j) {
                    const int col = wc * 64 + j * 16 + l15;
                    #pragma unroll
                    for (int r = 0; r < 4; ++r) {
                        const int lrow = ii * 16 + l4 * 4 + r;
                        fS[lrow * 132 + col] = fmaxf(acc[ib + ii][j][r] * descale + bvj[j], 0.f);
                    }
                }
            }
        }
        __syncthreads();
        const size_t grow = rowA0 + p * 64 + rr;
        #pragma unroll
        for (int m = 0; m < 4; ++m) {
            const float* src = fS + rr * 132 + c0 + m * 32;
            float a0 = fminf(src[0] * osc, 448.f);
            float a1 = fminf(src[1] * osc, 448.f);
            float a2 = fminf(src[2] * osc, 448.f);
            float a3 = fminf(src[3] * osc, 448.f);
            float a4 = fminf(src[4] * osc, 448.f);
            float a5 = fminf(src[5] * osc, 448.f);
            float a6 = fminf(src[6] * osc, 448.f);
            float a7 = fminf(src[7] * osc, 448.f);
            int lo = pk8h(a2, a3, pk8(a0, a1, 0));
            int hi = pk8h(a6, a7, pk8(a4, a5, 0));
            *(int2*)(out + grow * (size_t)N + rowB0 + c0 + m * 32) = make_int2(lo, hi);
        }
    }
}

// ---------- GEMM3 + finale fused (fp8 inputs): 64 rows/block, B via LDS ----------
__global__ __launch_bounds__(256, 3)
void gemm3_fused(const unsigned char* __restrict__ A,   // h2 [B,1024] fp8
                 const unsigned char* __restrict__ Wt,  // W3 [128,1024] fp8
                 const float* __restrict__ bias,        // [128]
                 const float* __restrict__ eps,         // [B,64]
                 float* __restrict__ act_out, float* __restrict__ logp_out,
                 float descale, int K) {
    __shared__ char smem[32768];
    char* lA = smem;             // 64x128 B = 8 KB
    char* lB = smem + 8192;      // 128x128 B = 16 KB
    float* fmu = (float*)smem;            // epilogue 64x64 f32
    float* fls = (float*)(smem + 16384);
    const int tid  = threadIdx.x;
    const int wv   = tid >> 6, lane = tid & 63;
    const int wr   = wv >> 1,  wc   = wv & 1;     // wave: 32 rows x 64 cols
    const int l15  = lane & 15, l4  = lane >> 4;
    const size_t rowA0 = (size_t)blockIdx.x * 64;
    const unsigned char* Ab = A + rowA0 * K;
    const int qsw = ((tid & 7) ^ ((tid >> 3) & 7)) * 16;
    const int srow = tid >> 3;
    const int p0 = ((l4 * 2) ^ (l15 & 7)) * 16;
    const int p1 = ((l4 * 2 + 1) ^ (l15 & 7)) * 16;

    f32x4 acc[2][4];
    #pragma unroll
    for (int i = 0; i < 2; ++i)
        #pragma unroll
        for (int j = 0; j < 4; ++j)
            acc[i][j] = f32x4{0.f, 0.f, 0.f, 0.f};

    for (int k0 = 0; k0 < K; k0 += 128) {
        #pragma unroll
        for (int c = 0; c < 2; ++c)
            g2l16(Ab + (size_t)(c * 32 + srow) * K + k0 + qsw, lA + c * 4096 + tid * 16);
        #pragma unroll
        for (int c = 0; c < 4; ++c)
            g2l16(Wt + (size_t)(c * 32 + srow) * K + k0 + qsw, lB + c * 4096 + tid * 16);
        __syncthreads();
        union { v8i v; v4i h[2]; } af[2], bfr[4];
        #pragma unroll
        for (int i = 0; i < 2; ++i) {
            const char* ar = lA + (wr * 32 + i * 16 + l15) * 128;
            af[i].h[0] = *(const v4i*)(ar + p0);
            af[i].h[1] = *(const v4i*)(ar + p1);
        }
        #pragma unroll
        for (int j = 0; j < 4; ++j) {
            const char* br = lB + (wc * 64 + j * 16 + l15) * 128;
            bfr[j].h[0] = *(const v4i*)(br + p0);
            bfr[j].h[1] = *(const v4i*)(br + p1);
        }
        #pragma unroll
        for (int i = 0; i < 2; ++i)
            #pragma unroll
            for (int j = 0; j < 4; ++j)
                acc[i][j] = __builtin_amdgcn_mfma_scale_f32_16x16x128_f8f6f4(
                    af[i].v, bfr[j].v, acc[i][j], 0, 0, 0, 0x7F7F7F7F, 0, 0x7F7F7F7F);
        __syncthreads();
    }

    // Epilogue: cols 0..63 = mu (wc=0), 64..127 = log_std (wc=1); +row rotation in LDS
    {
        float* dst = wc ? fls : fmu;
        #pragma unroll
        for (int i = 0; i < 2; ++i) {
            #pragma unroll
            for (int j = 0; j < 4; ++j) {
                int c = j * 16 + l15;                 // 0..63
                float bv = bias[wc * 64 + c];
                #pragma unroll
                for (int r = 0; r < 4; ++r) {
                    int lr = wr * 32 + i * 16 + l4 * 4 + r;   // 0..63
                    dst[lr * 64 + ((c + lr) & 63)] = acc[i][j][r] * descale + bv;
                }
            }
        }
    }
    __syncthreads();
    {
        int r = tid >> 2;                              // 0..63
        size_t grow = rowA0 + r;
        float lp = 0.f;
        #pragma unroll
        for (int t = 0; t < 16; ++t) {
            int j = (tid & 3) * 16 + t;                // 0..63
            int rot = (j + r) & 63;
            float mu = fmu[r * 64 + rot];
            float ls = fls[r * 64 + rot];
            ls = fminf(fmaxf(ls, -20.f), 2.f);
            float sd = expf(ls);
            float e  = eps[grow * 64 + j];
            float pi = fmaf(sd, e, mu);
            act_out[grow * 64 + j] = tanhf(pi);
            lp += -0.5f * e * e - ls - 0.91893853320467274178f;
            float xn = -2.f * pi;
            float sp = fmaxf(xn, 0.f) + log1pf(expf(-fabsf(xn)));
            lp -= 2.f * (0.69314718055994530942f - pi - sp);
        }
        lp += __shfl_xor(lp, 1);
        lp += __shfl_xor(lp, 2);
        if ((tid & 3) == 0) logp_out[grow] = lp;
    }
}

// ---------- launch ----------
extern "C" void kernel_launch(void* const* d_in, const int* in_sizes, int n_in,
                              void* d_out, int out_size, void* d_ws, size_t ws_size,
                              hipStream_t stream) {
    const float* obs = (const float*)d_in[0];
    const float* eps = (const float*)d_in[1];
    const float* W1  = (const float*)d_in[2];
    const float* b1  = (const float*)d_in[3];
    const float* W2  = (const float*)d_in[4];
    const float* b2  = (const float*)d_in[5];
    const float* W3  = (const float*)d_in[6];
    const float* b3  = (const float*)d_in[7];
    const int B = 32768, OBS = 512, H1 = 1024, H2 = 1024;

    char* ws = (char*)d_ws;
    unsigned char* x8  = (unsigned char*)(ws);               // 16 MB [B*512]
    unsigned char* h1  = (unsigned char*)(ws + 16777216);    // 32 MB
    unsigned char* h2  = (unsigned char*)(ws + 50331648);    // 32 MB
    unsigned char* W1s = (unsigned char*)(ws + 83886080);    // 512 KB
    unsigned char* W2s = (unsigned char*)(ws + 84410368);    // 1 MB
    unsigned char* W3s = (unsigned char*)(ws + 85458944);    // 128 KB
    float*         b1q = (float*)(ws + 85590016);
    float*         b2q = (float*)(ws + 85594112);
    float*         b3q = (float*)(ws + 85598208);
    float*         pmax = (float*)(ws + 85598720);           // 288 floats

    prep_cvt<<<8480, 256, 0, stream>>>(W1, W2, W3, pmax, obs, x8);
    quant_all<<<833, 256, 0, stream>>>(W1, W2, W3, b1, b2, b3,
                                       W1s, W2s, W3s, b1q, b2q, b3q, pmax);

    // scale bookkeeping (all powers of 2, exact):
    //   W* stored *2^10 ; x stored *1 (s_in^2 folded into descale1)
    //   h1 stored *2^24 ; h2 stored *2^22
    const float desc1 = (float)((1.0 / 12000.0) * (1.0 / 12000.0) / 1024.0);
    const float osc1  = 16777216.f;                   // 2^24
    const float desc2 = 1.0f / 17179869184.f;         // 2^-34
    const float osc2  = 4194304.f;                    // 2^22
    const float desc3 = (float)(1.0 / 4294967296.0);  // 2^-32

    gemm8<3><<<dim3(8, 128), 256, 0, stream>>>(x8, W1s, b1q, h1, desc1, osc1, H1, OBS);
    gemm8<3><<<dim3(8, 128), 256, 0, stream>>>(h1, W2s, b2q, h2, desc2, osc2, H2, H1);

    float* act_out  = (float*)d_out;
    float* logp_out = act_out + (size_t)B * 64;
    gemm3_fused<<<512, 256, 0, stream>>>(h2, W3s, b3q, eps, act_out, logp_out, desc3, H2);
}

// Round 8
// 216.451 us; speedup vs baseline: 1.1379x; 1.0257x over previous
//
#include <hip/hip_runtime.h>
#include <math.h>

typedef float f32x4 __attribute__((ext_vector_type(4)));
typedef int   v4i   __attribute__((ext_vector_type(4)));
typedef int   v8i   __attribute__((ext_vector_type(8)));

// ---------- helpers ----------
__device__ __forceinline__ void g2l16(const void* g, void* l) {
    // async global->LDS, 16B per lane; LDS dest = wave-uniform base + lane*16
    __builtin_amdgcn_global_load_lds(
        (__attribute__((address_space(1))) void*)g,
        (__attribute__((address_space(3))) void*)l,
        16, 0, 0);
}

__device__ __forceinline__ int pk8(float a, float b, int old) {
    return __builtin_amdgcn_cvt_pk_fp8_f32(a, b, old, 0);
}
__device__ __forceinline__ int pk8h(float a, float b, int old) {
    return __builtin_amdgcn_cvt_pk_fp8_f32(a, b, old, 1);
}

// 4x4 transpose across a lane quad (local col c = lane&3), regs = rows.
// In: v[r] = M[r][c]. Out: v[k] = M[c][k]. Verified element-wise.
__device__ __forceinline__ void quad_transpose(f32x4& v, int c) {
    float s0 = __shfl_xor(v[1], 1);
    float s1 = __shfl_xor(v[0], 1);
    float s2 = __shfl_xor(v[3], 1);
    float s3 = __shfl_xor(v[2], 1);
    bool b0 = (c & 1);
    f32x4 t;
    t[0] = b0 ? s0 : v[0];
    t[1] = b0 ? v[1] : s1;
    t[2] = b0 ? s2 : v[2];
    t[3] = b0 ? v[3] : s3;
    float u0 = __shfl_xor(t[2], 2);
    float u1 = __shfl_xor(t[3], 2);
    float u2 = __shfl_xor(t[0], 2);
    float u3 = __shfl_xor(t[1], 2);
    bool b1 = (c & 2);
    v[0] = b1 ? u0 : t[0];
    v[1] = b1 ? u1 : t[1];
    v[2] = b1 ? t[2] : u2;
    v[3] = b1 ? t[3] : u3;
}

// ---------- kernel 1: absmax partials (blocks 0..287) + obs->fp8 (blocks 288..8479) ----------
__global__ void prep_cvt(const float* __restrict__ W1, const float* __restrict__ W2,
                         const float* __restrict__ W3, float* __restrict__ pmax,
                         const float* __restrict__ obs, unsigned char* __restrict__ x8) {
    if (blockIdx.x < 288) {
        int blk = blockIdx.x;
        const float* w; int n, b, nb;
        if (blk < 128)      { w = W1; n = 524288;  b = blk;       nb = 128; }
        else if (blk < 256) { w = W2; n = 1048576; b = blk - 128; nb = 128; }
        else                { w = W3; n = 131072;  b = blk - 256; nb = 32;  }
        float m = 0.f;
        for (int i = b * 256 + threadIdx.x; i < n; i += nb * 256)
            m = fmaxf(m, fabsf(w[i]));
        #pragma unroll
        for (int off = 32; off; off >>= 1)
            m = fmaxf(m, __shfl_down(m, off));
        __shared__ float sm[4];
        int lane = threadIdx.x & 63, wv = threadIdx.x >> 6;
        if (lane == 0) sm[wv] = m;
        __syncthreads();
        if (threadIdx.x == 0)
            pmax[blockIdx.x] = fmaxf(fmaxf(sm[0], sm[1]), fmaxf(sm[2], sm[3]));
    } else {
        int i = ((blockIdx.x - 288) * 256 + threadIdx.x) * 8;
        float4 a = *(const float4*)(obs + i);
        float4 c = *(const float4*)(obs + i + 4);
        int lo = pk8(a.x, a.y, 0); lo = pk8h(a.z, a.w, lo);
        int hi = pk8(c.x, c.y, 0); hi = pk8h(c.z, c.w, hi);
        *(int2*)(x8 + i) = make_int2(lo, hi);
    }
}

// uniform per-block reduction of a pmax segment (all threads return the max)
__device__ __forceinline__ float seg_max(const float* __restrict__ pmax, int base, int cnt,
                                         float* sm) {
    int tid = threadIdx.x, lane = tid & 63, wv = tid >> 6;
    float m = (tid < cnt) ? pmax[base + tid] : 0.f;
    #pragma unroll
    for (int off = 32; off; off >>= 1)
        m = fmaxf(m, __shfl_down(m, off));
    if (lane == 0) sm[wv] = m;
    __syncthreads();
    float r = fmaxf(fmaxf(sm[0], sm[1]), fmaxf(sm[2], sm[3]));
    __syncthreads();
    return r;
}

// ---------- kernel 2: quantize weights -> fp8(q*ws*2^10); block 832 quantizes biases ----------
__global__ void quant_all(const float* __restrict__ W1, const float* __restrict__ W2,
                          const float* __restrict__ W3,
                          const float* __restrict__ b1, const float* __restrict__ b2,
                          const float* __restrict__ b3,
                          unsigned char* __restrict__ W1s, unsigned char* __restrict__ W2s,
                          unsigned char* __restrict__ W3s,
                          float* __restrict__ b1q, float* __restrict__ b2q, float* __restrict__ b3q,
                          const float* __restrict__ pmax) {
    __shared__ float sm[4];
    int b = blockIdx.x, tid = threadIdx.x;
    if (b < 832) {
        const float* w; unsigned char* o; int base, pb, pc;
        if (b < 256)      { w = W1; o = W1s; base = b * 2048;         pb = 0;   pc = 128; }
        else if (b < 768) { w = W2; o = W2s; base = (b - 256) * 2048; pb = 128; pc = 128; }
        else              { w = W3; o = W3s; base = (b - 768) * 2048; pb = 256; pc = 32;  }
        float s = seg_max(pmax, pb, pc, sm) / 127.0f;
        int i = base + tid * 8;
        float4 a = *(const float4*)(w + i);
        float4 c = *(const float4*)(w + i + 4);
        #define QW(x) fminf(fmaxf(fminf(fmaxf(rintf((x) / s), -127.f), 127.f) * s * 1024.f, -448.f), 448.f)
        int lo = pk8(QW(a.x), QW(a.y), 0); lo = pk8h(QW(a.z), QW(a.w), lo);
        int hi = pk8(QW(c.x), QW(c.y), 0); hi = pk8h(QW(c.z), QW(c.w), hi);
        #undef QW
        *(int2*)(o + i) = make_int2(lo, hi);
    } else {
        float ws1 = seg_max(pmax, 0, 128, sm) / 127.0f;
        float ws2 = seg_max(pmax, 128, 128, sm) / 127.0f;
        float ws3 = seg_max(pmax, 256, 32, sm) / 127.0f;
        const float s_in = (float)(1.0 / 12000.0);
        float sb1 = s_in * ws1;
        float sb2 = sb1 * ws2;
        float sb3 = sb2 * ws3;
        for (int i = tid; i < 1024; i += 256) {
            b1q[i] = fminf(fmaxf(rintf(b1[i] / sb1), -128.f), 127.f) * sb1;
            b2q[i] = fminf(fmaxf(rintf(b2[i] / sb2), -128.f), 127.f) * sb2;
        }
        if (tid < 128) b3q[tid] = fminf(fmaxf(rintf(b3[tid] / sb3), -128.f), 127.f) * sb3;
    }
}

// ---------- MX-fp8 GEMM: out_fp8 = fp8( relu(A@Wt^T * descale + bias) * osc ) ----------
// Block 256(M)x128(N), BK=128 B. A/B staged via global_load_lds with xor-chunk
// swizzle. Epilogue: in-register quad transpose (DPP shfl, no LDS, no barriers),
// fp8 pack, dword stores (16-B row segments).
template <int LGX>
__global__ __launch_bounds__(256, 2)
void gemm8(const unsigned char* __restrict__ A,   // [M,K] fp8
           const unsigned char* __restrict__ Wt,  // [N,K] fp8 (pre-scaled 2^10)
           const float* __restrict__ bias,        // [N] f32
           unsigned char* __restrict__ out,       // [M,N] fp8
           float descale, float osc, int N, int K) {
    __shared__ char smem[49152];
    char* lA = smem;            // 256x128 B = 32 KB
    char* lB = smem + 32768;    // 128x128 B = 16 KB
    const int tid  = threadIdx.x;
    const int wv   = tid >> 6, lane = tid & 63;
    const int wr   = wv >> 1,  wc   = wv & 1;     // wave: 128 rows x 64 cols
    const int l15  = lane & 15, l4  = lane >> 4;
    const int lid  = blockIdx.y * gridDim.x + blockIdx.x;
    const int xcd  = lid & 7;
    const int s    = lid >> 3;
    const int mblk = (s >> LGX) * 8 + xcd;
    const int nblk = s & ((1 << LGX) - 1);
    const size_t rowA0 = (size_t)mblk * 256;
    const size_t rowB0 = (size_t)nblk * 128;
    const unsigned char* Ab = A  + rowA0 * K;
    const unsigned char* Bb = Wt + rowB0 * K;
    const int qsw = ((tid & 7) ^ ((tid >> 3) & 7)) * 16;   // swizzled src chunk offset
    const int srow = tid >> 3;                             // 0..31

    f32x4 acc[8][4];
    #pragma unroll
    for (int i = 0; i < 8; ++i)
        #pragma unroll
        for (int j = 0; j < 4; ++j)
            acc[i][j] = f32x4{0.f, 0.f, 0.f, 0.f};

    const int p0 = ((l4 * 2) ^ (l15 & 7)) * 16;       // LDS chunk of k-lo 16B
    const int p1 = ((l4 * 2 + 1) ^ (l15 & 7)) * 16;   // LDS chunk of k-hi 16B

    for (int k0 = 0; k0 < K; k0 += 128) {
        #pragma unroll
        for (int c = 0; c < 8; ++c)
            g2l16(Ab + (size_t)(c * 32 + srow) * K + k0 + qsw, lA + c * 4096 + tid * 16);
        #pragma unroll
        for (int c = 0; c < 4; ++c)
            g2l16(Bb + (size_t)(c * 32 + srow) * K + k0 + qsw, lB + c * 4096 + tid * 16);
        __syncthreads();
        union { v8i v; v4i h[2]; } bfr[4];
        #pragma unroll
        for (int j = 0; j < 4; ++j) {
            const char* br = lB + (wc * 64 + j * 16 + l15) * 128;
            bfr[j].h[0] = *(const v4i*)(br + p0);
            bfr[j].h[1] = *(const v4i*)(br + p1);
        }
        #pragma unroll
        for (int i = 0; i < 8; ++i) {
            const char* ar = lA + (wr * 128 + i * 16 + l15) * 128;
            union { v8i v; v4i h[2]; } af;
            af.h[0] = *(const v4i*)(ar + p0);
            af.h[1] = *(const v4i*)(ar + p1);
            #pragma unroll
            for (int j = 0; j < 4; ++j)
                acc[i][j] = __builtin_amdgcn_mfma_scale_f32_16x16x128_f8f6f4(
                    af.v, bfr[j].v, acc[i][j], 0, 0, 0, 0x7F7F7F7F, 0, 0x7F7F7F7F);
        }
        __syncthreads();
    }

    // Epilogue: bias+relu+osc in C-layout, quad-transpose to row-major, pack, store.
    const int c2 = l15 & 3;
    float bvj[4];
    #pragma unroll
    for (int j = 0; j < 4; ++j) bvj[j] = bias[rowB0 + wc * 64 + j * 16 + l15];
    #pragma unroll
    for (int i = 0; i < 8; ++i) {
        const size_t grow = rowA0 + wr * 128 + i * 16 + l4 * 4 + c2;
        #pragma unroll
        for (int j = 0; j < 4; ++j) {
            f32x4 v;
            #pragma unroll
            for (int r = 0; r < 4; ++r)
                v[r] = fminf(fmaxf(acc[i][j][r] * descale + bvj[j], 0.f) * osc, 448.f);
            quad_transpose(v, c2);
            int d = pk8h(v[2], v[3], pk8(v[0], v[1], 0));
            *(int*)(out + grow * (size_t)N + rowB0 + wc * 64 + j * 16 + (l15 & ~3)) = d;
        }
    }
}

// ---------- GEMM3 + finale fused (fp8 inputs): 64 rows/block, B via LDS ----------
__global__ __launch_bounds__(256, 3)
void gemm3_fused(const unsigned char* __restrict__ A,   // h2 [B,1024] fp8
                 const unsigned char* __restrict__ Wt,  // W3 [128,1024] fp8
                 const float* __restrict__ bias,        // [128]
                 const float* __restrict__ eps,         // [B,64]
                 float* __restrict__ act_out, float* __restrict__ logp_out,
                 float descale, int K) {
    __shared__ char smem[32768];
    char* lA = smem;             // 64x128 B = 8 KB
    char* lB = smem + 8192;      // 128x128 B = 16 KB
    float* fmu = (float*)smem;            // epilogue 64x64 f32
    float* fls = (float*)(smem + 16384);
    const int tid  = threadIdx.x;
    const int wv   = tid >> 6, lane = tid & 63;
    const int wr   = wv >> 1,  wc   = wv & 1;     // wave: 32 rows x 64 cols
    const int l15  = lane & 15, l4  = lane >> 4;
    const size_t rowA0 = (size_t)blockIdx.x * 64;
    const unsigned char* Ab = A + rowA0 * K;
    const int qsw = ((tid & 7) ^ ((tid >> 3) & 7)) * 16;
    const int srow = tid >> 3;
    const int p0 = ((l4 * 2) ^ (l15 & 7)) * 16;
    const int p1 = ((l4 * 2 + 1) ^ (l15 & 7)) * 16;

    f32x4 acc[2][4];
    #pragma unroll
    for (int i = 0; i < 2; ++i)
        #pragma unroll
        for (int j = 0; j < 4; ++j)
            acc[i][j] = f32x4{0.f, 0.f, 0.f, 0.f};

    for (int k0 = 0; k0 < K; k0 += 128) {
        #pragma unroll
        for (int c = 0; c < 2; ++c)
            g2l16(Ab + (size_t)(c * 32 + srow) * K + k0 + qsw, lA + c * 4096 + tid * 16);
        #pragma unroll
        for (int c = 0; c < 4; ++c)
            g2l16(Wt + (size_t)(c * 32 + srow) * K + k0 + qsw, lB + c * 4096 + tid * 16);
        __syncthreads();
        union { v8i v; v4i h[2]; } af[2], bfr[4];
        #pragma unroll
        for (int i = 0; i < 2; ++i) {
            const char* ar = lA + (wr * 32 + i * 16 + l15) * 128;
            af[i].h[0] = *(const v4i*)(ar + p0);
            af[i].h[1] = *(const v4i*)(ar + p1);
        }
        #pragma unroll
        for (int j = 0; j < 4; ++j) {
            const char* br = lB + (wc * 64 + j * 16 + l15) * 128;
            bfr[j].h[0] = *(const v4i*)(br + p0);
            bfr[j].h[1] = *(const v4i*)(br + p1);
        }
        #pragma unroll
        for (int i = 0; i < 2; ++i)
            #pragma unroll
            for (int j = 0; j < 4; ++j)
                acc[i][j] = __builtin_amdgcn_mfma_scale_f32_16x16x128_f8f6f4(
                    af[i].v, bfr[j].v, acc[i][j], 0, 0, 0, 0x7F7F7F7F, 0, 0x7F7F7F7F);
        __syncthreads();
    }

    // Epilogue: cols 0..63 = mu (wc=0), 64..127 = log_std (wc=1); +row rotation in LDS
    {
        float* dst = wc ? fls : fmu;
        #pragma unroll
        for (int i = 0; i < 2; ++i) {
            #pragma unroll
            for (int j = 0; j < 4; ++j) {
                int c = j * 16 + l15;                 // 0..63
                float bv = bias[wc * 64 + c];
                #pragma unroll
                for (int r = 0; r < 4; ++r) {
                    int lr = wr * 32 + i * 16 + l4 * 4 + r;   // 0..63
                    dst[lr * 64 + ((c + lr) & 63)] = acc[i][j][r] * descale + bv;
                }
            }
        }
    }
    __syncthreads();
    {
        int r = tid >> 2;                              // 0..63
        size_t grow = rowA0 + r;
        float lp = 0.f;
        #pragma unroll
        for (int t = 0; t < 4; ++t) {
            int j0 = (tid & 3) * 16 + t * 4;           // float4-aligned col chunk
            float4 e4 = *(const float4*)(eps + grow * 64 + j0);
            float ев[4] = {e4.x, e4.y, e4.z, e4.w};
            float a4[4];
            #pragma unroll
            for (int k = 0; k < 4; ++k) {
                int j = j0 + k;
                int rot = (j + r) & 63;
                float mu = fmu[r * 64 + rot];
                float ls = fls[r * 64 + rot];
                ls = fminf(fmaxf(ls, -20.f), 2.f);
                float sd = expf(ls);
                float e  = ев[k];
                float pi = fmaf(sd, e, mu);
                a4[k] = tanhf(pi);
                lp += -0.5f * e * e - ls - 0.91893853320467274178f;
                float xn = -2.f * pi;
                float sp = fmaxf(xn, 0.f) + log1pf(expf(-fabsf(xn)));
                lp -= 2.f * (0.69314718055994530942f - pi - sp);
            }
            *(float4*)(act_out + grow * 64 + j0) = make_float4(a4[0], a4[1], a4[2], a4[3]);
        }
        lp += __shfl_xor(lp, 1);
        lp += __shfl_xor(lp, 2);
        if ((tid & 3) == 0) logp_out[grow] = lp;
    }
}

// ---------- launch ----------
extern "C" void kernel_launch(void* const* d_in, const int* in_sizes, int n_in,
                              void* d_out, int out_size, void* d_ws, size_t ws_size,
                              hipStream_t stream) {
    const float* obs = (const float*)d_in[0];
    const float* eps = (const float*)d_in[1];
    const float* W1  = (const float*)d_in[2];
    const float* b1  = (const float*)d_in[3];
    const float* W2  = (const float*)d_in[4];
    const float* b2  = (const float*)d_in[5];
    const float* W3  = (const float*)d_in[6];
    const float* b3  = (const float*)d_in[7];
    const int B = 32768, OBS = 512, H1 = 1024, H2 = 1024;

    char* ws = (char*)d_ws;
    unsigned char* x8  = (unsigned char*)(ws);               // 16 MB [B*512]
    unsigned char* h1  = (unsigned char*)(ws + 16777216);    // 32 MB
    unsigned char* h2  = (unsigned char*)(ws + 50331648);    // 32 MB
    unsigned char* W1s = (unsigned char*)(ws + 83886080);    // 512 KB
    unsigned char* W2s = (unsigned char*)(ws + 84410368);    // 1 MB
    unsigned char* W3s = (unsigned char*)(ws + 85458944);    // 128 KB
    float*         b1q = (float*)(ws + 85590016);
    float*         b2q = (float*)(ws + 85594112);
    float*         b3q = (float*)(ws + 85598208);
    float*         pmax = (float*)(ws + 85598720);           // 288 floats

    prep_cvt<<<8480, 256, 0, stream>>>(W1, W2, W3, pmax, obs, x8);
    quant_all<<<833, 256, 0, stream>>>(W1, W2, W3, b1, b2, b3,
                                       W1s, W2s, W3s, b1q, b2q, b3q, pmax);

    // scale bookkeeping (all powers of 2, exact):
    //   W* stored *2^10 ; x stored *1 (s_in^2 folded into descale1)
    //   h1 stored *2^24 ; h2 stored *2^22
    const float desc1 = (float)((1.0 / 12000.0) * (1.0 / 12000.0) / 1024.0);
    const float osc1  = 16777216.f;                   // 2^24
    const float desc2 = 1.0f / 17179869184.f;         // 2^-34
    const float osc2  = 4194304.f;                    // 2^22
    const float desc3 = (float)(1.0 / 4294967296.0);  // 2^-32

    gemm8<3><<<dim3(8, 128), 256, 0, stream>>>(x8, W1s, b1q, h1, desc1, osc1, H1, OBS);
    gemm8<3><<<dim3(8, 128), 256, 0, stream>>>(h1, W2s, b2q, h2, desc2, osc2, H2, H1);

    float* act_out  = (float*)d_out;
    float* logp_out = act_out + (size_t)B * 64;
    gemm3_fused<<<512, 256, 0, stream>>>(h2, W3s, b3q, eps, act_out, logp_out, desc3, H2);
}

// Round 9
// 216.386 us; speedup vs baseline: 1.1382x; 1.0003x over previous
//
#include <hip/hip_runtime.h>
#include <math.h>

typedef float f32x4 __attribute__((ext_vector_type(4)));
typedef int   v4i   __attribute__((ext_vector_type(4)));
typedef int   v8i   __attribute__((ext_vector_type(8)));

// ---------- helpers ----------
__device__ __forceinline__ void g2l16(const void* g, void* l) {
    // async global->LDS, 16B per lane; LDS dest = wave-uniform base + lane*16
    __builtin_amdgcn_global_load_lds(
        (__attribute__((address_space(1))) void*)g,
        (__attribute__((address_space(3))) void*)l,
        16, 0, 0);
}

__device__ __forceinline__ int pk8(float a, float b, int old) {
    return __builtin_amdgcn_cvt_pk_fp8_f32(a, b, old, 0);
}
__device__ __forceinline__ int pk8h(float a, float b, int old) {
    return __builtin_amdgcn_cvt_pk_fp8_f32(a, b, old, 1);
}

// ---------- kernel 1: absmax partials (blocks 0..287) + obs->fp8 (blocks 288..8479) ----------
__global__ void prep_cvt(const float* __restrict__ W1, const float* __restrict__ W2,
                         const float* __restrict__ W3, float* __restrict__ pmax,
                         const float* __restrict__ obs, unsigned char* __restrict__ x8) {
    if (blockIdx.x < 288) {
        int blk = blockIdx.x;
        const float* w; int n, b, nb;
        if (blk < 128)      { w = W1; n = 524288;  b = blk;       nb = 128; }
        else if (blk < 256) { w = W2; n = 1048576; b = blk - 128; nb = 128; }
        else                { w = W3; n = 131072;  b = blk - 256; nb = 32;  }
        float m = 0.f;
        for (int i = b * 256 + threadIdx.x; i < n; i += nb * 256)
            m = fmaxf(m, fabsf(w[i]));
        #pragma unroll
        for (int off = 32; off; off >>= 1)
            m = fmaxf(m, __shfl_down(m, off));
        __shared__ float sm[4];
        int lane = threadIdx.x & 63, wv = threadIdx.x >> 6;
        if (lane == 0) sm[wv] = m;
        __syncthreads();
        if (threadIdx.x == 0)
            pmax[blockIdx.x] = fmaxf(fmaxf(sm[0], sm[1]), fmaxf(sm[2], sm[3]));
    } else {
        int i = ((blockIdx.x - 288) * 256 + threadIdx.x) * 8;
        float4 a = *(const float4*)(obs + i);
        float4 c = *(const float4*)(obs + i + 4);
        int lo = pk8(a.x, a.y, 0); lo = pk8h(a.z, a.w, lo);
        int hi = pk8(c.x, c.y, 0); hi = pk8h(c.z, c.w, hi);
        *(int2*)(x8 + i) = make_int2(lo, hi);
    }
}

// uniform per-block reduction of a pmax segment (all threads return the max)
__device__ __forceinline__ float seg_max(const float* __restrict__ pmax, int base, int cnt,
                                         float* sm) {
    int tid = threadIdx.x, lane = tid & 63, wv = tid >> 6;
    float m = (tid < cnt) ? pmax[base + tid] : 0.f;
    #pragma unroll
    for (int off = 32; off; off >>= 1)
        m = fmaxf(m, __shfl_down(m, off));
    if (lane == 0) sm[wv] = m;
    __syncthreads();
    float r = fmaxf(fmaxf(sm[0], sm[1]), fmaxf(sm[2], sm[3]));
    __syncthreads();
    return r;
}

// ---------- kernel 2: quantize weights -> fp8(q*ws*2^10); block 832 quantizes biases ----------
__global__ void quant_all(const float* __restrict__ W1, const float* __restrict__ W2,
                          const float* __restrict__ W3,
                          const float* __restrict__ b1, const float* __restrict__ b2,
                          const float* __restrict__ b3,
                          unsigned char* __restrict__ W1s, unsigned char* __restrict__ W2s,
                          unsigned char* __restrict__ W3s,
                          float* __restrict__ b1q, float* __restrict__ b2q, float* __restrict__ b3q,
                          const float* __restrict__ pmax) {
    __shared__ float sm[4];
    int b = blockIdx.x, tid = threadIdx.x;
    if (b < 832) {
        const float* w; unsigned char* o; int base, pb, pc;
        if (b < 256)      { w = W1; o = W1s; base = b * 2048;         pb = 0;   pc = 128; }
        else if (b < 768) { w = W2; o = W2s; base = (b - 256) * 2048; pb = 128; pc = 128; }
        else              { w = W3; o = W3s; base = (b - 768) * 2048; pb = 256; pc = 32;  }
        float s = seg_max(pmax, pb, pc, sm) / 127.0f;
        int i = base + tid * 8;
        float4 a = *(const float4*)(w + i);
        float4 c = *(const float4*)(w + i + 4);
        #define QW(x) fminf(fmaxf(fminf(fmaxf(rintf((x) / s), -127.f), 127.f) * s * 1024.f, -448.f), 448.f)
        int lo = pk8(QW(a.x), QW(a.y), 0); lo = pk8h(QW(a.z), QW(a.w), lo);
        int hi = pk8(QW(c.x), QW(c.y), 0); hi = pk8h(QW(c.z), QW(c.w), hi);
        #undef QW
        *(int2*)(o + i) = make_int2(lo, hi);
    } else {
        float ws1 = seg_max(pmax, 0, 128, sm) / 127.0f;
        float ws2 = seg_max(pmax, 128, 128, sm) / 127.0f;
        float ws3 = seg_max(pmax, 256, 32, sm) / 127.0f;
        const float s_in = (float)(1.0 / 12000.0);
        float sb1 = s_in * ws1;
        float sb2 = sb1 * ws2;
        float sb3 = sb2 * ws3;
        for (int i = tid; i < 1024; i += 256) {
            b1q[i] = fminf(fmaxf(rintf(b1[i] / sb1), -128.f), 127.f) * sb1;
            b2q[i] = fminf(fmaxf(rintf(b2[i] / sb2), -128.f), 127.f) * sb2;
        }
        if (tid < 128) b3q[tid] = fminf(fmaxf(rintf(b3[tid] / sb3), -128.f), 127.f) * sb3;
    }
}

// ---------- MX-fp8 GEMM: out_fp8 = fp8( relu(A@Wt^T * descale + bias) * osc ) ----------
// Block 256(M)x128(N), BK=128 B. A/B staged via global_load_lds with xor-chunk
// swizzle. Epilogue: padded LDS rows (132 f32), 8-float read chunks strided 32
// cols, int2 fp8 stores (round-7 pattern; measured 42.3 us vs 46.5 for the
// in-register transpose variant).
template <int LGX>
__global__ __launch_bounds__(256, 2)
void gemm8(const unsigned char* __restrict__ A,   // [M,K] fp8
           const unsigned char* __restrict__ Wt,  // [N,K] fp8 (pre-scaled 2^10)
           const float* __restrict__ bias,        // [N] f32
           unsigned char* __restrict__ out,       // [M,N] fp8
           float descale, float osc, int N, int K) {
    __shared__ char smem[49152];
    char* lA = smem;            // 256x128 B = 32 KB
    char* lB = smem + 32768;    // 128x128 B = 16 KB
    const int tid  = threadIdx.x;
    const int wv   = tid >> 6, lane = tid & 63;
    const int wr   = wv >> 1,  wc   = wv & 1;     // wave: 128 rows x 64 cols
    const int l15  = lane & 15, l4  = lane >> 4;
    const int lid  = blockIdx.y * gridDim.x + blockIdx.x;
    const int xcd  = lid & 7;
    const int s    = lid >> 3;
    const int mblk = (s >> LGX) * 8 + xcd;
    const int nblk = s & ((1 << LGX) - 1);
    const size_t rowA0 = (size_t)mblk * 256;
    const size_t rowB0 = (size_t)nblk * 128;
    const unsigned char* Ab = A  + rowA0 * K;
    const unsigned char* Bb = Wt + rowB0 * K;
    const int qsw = ((tid & 7) ^ ((tid >> 3) & 7)) * 16;   // swizzled src chunk offset
    const int srow = tid >> 3;                             // 0..31

    f32x4 acc[8][4];
    #pragma unroll
    for (int i = 0; i < 8; ++i)
        #pragma unroll
        for (int j = 0; j < 4; ++j)
            acc[i][j] = f32x4{0.f, 0.f, 0.f, 0.f};

    const int p0 = ((l4 * 2) ^ (l15 & 7)) * 16;       // LDS chunk of k-lo 16B
    const int p1 = ((l4 * 2 + 1) ^ (l15 & 7)) * 16;   // LDS chunk of k-hi 16B

    for (int k0 = 0; k0 < K; k0 += 128) {
        #pragma unroll
        for (int c = 0; c < 8; ++c)
            g2l16(Ab + (size_t)(c * 32 + srow) * K + k0 + qsw, lA + c * 4096 + tid * 16);
        #pragma unroll
        for (int c = 0; c < 4; ++c)
            g2l16(Bb + (size_t)(c * 32 + srow) * K + k0 + qsw, lB + c * 4096 + tid * 16);
        __syncthreads();
        union { v8i v; v4i h[2]; } bfr[4];
        #pragma unroll
        for (int j = 0; j < 4; ++j) {
            const char* br = lB + (wc * 64 + j * 16 + l15) * 128;
            bfr[j].h[0] = *(const v4i*)(br + p0);
            bfr[j].h[1] = *(const v4i*)(br + p1);
        }
        #pragma unroll
        for (int i = 0; i < 8; ++i) {
            const char* ar = lA + (wr * 128 + i * 16 + l15) * 128;
            union { v8i v; v4i h[2]; } af;
            af.h[0] = *(const v4i*)(ar + p0);
            af.h[1] = *(const v4i*)(ar + p1);
            #pragma unroll
            for (int j = 0; j < 4; ++j)
                acc[i][j] = __builtin_amdgcn_mfma_scale_f32_16x16x128_f8f6f4(
                    af.v, bfr[j].v, acc[i][j], 0, 0, 0, 0x7F7F7F7F, 0, 0x7F7F7F7F);
        }
        __syncthreads();
    }

    // Epilogue: 4 bands of 64 rows via padded LDS (132 f32/row)
    float* fS = (float*)smem;
    const int rr = tid >> 2;                  // 0..63
    const int c0 = (tid & 3) * 8;             // 8-float chunks, strided 32 cols
    float bvj[4];
    #pragma unroll
    for (int j = 0; j < 4; ++j) bvj[j] = bias[rowB0 + wc * 64 + j * 16 + l15];
    #pragma unroll
    for (int p = 0; p < 4; ++p) {
        __syncthreads();
        if (wr == (p >> 1)) {
            const int ib = (p & 1) * 4;
            #pragma unroll
            for (int ii = 0; ii < 4; ++ii) {
                #pragma unroll
                for (int j = 0; j < 4; ++j) {
                    const int col = wc * 64 + j * 16 + l15;
                    #pragma unroll
                    for (int r = 0; r < 4; ++r) {
                        const int lrow = ii * 16 + l4 * 4 + r;
                        fS[lrow * 132 + col] = fmaxf(acc[ib + ii][j][r] * descale + bvj[j], 0.f);
                    }
                }
            }
        }
        __syncthreads();
        const size_t grow = rowA0 + p * 64 + rr;
        #pragma unroll
        for (int m = 0; m < 4; ++m) {
            const float* src = fS + rr * 132 + c0 + m * 32;
            float a0 = fminf(src[0] * osc, 448.f);
            float a1 = fminf(src[1] * osc, 448.f);
            float a2 = fminf(src[2] * osc, 448.f);
            float a3 = fminf(src[3] * osc, 448.f);
            float a4 = fminf(src[4] * osc, 448.f);
            float a5 = fminf(src[5] * osc, 448.f);
            float a6 = fminf(src[6] * osc, 448.f);
            float a7 = fminf(src[7] * osc, 448.f);
            int lo = pk8h(a2, a3, pk8(a0, a1, 0));
            int hi = pk8h(a6, a7, pk8(a4, a5, 0));
            *(int2*)(out + grow * (size_t)N + rowB0 + c0 + m * 32) = make_int2(lo, hi);
        }
    }
}

// ---------- GEMM3 + finale fused (fp8 inputs): 64 rows/block, B via LDS ----------
__global__ __launch_bounds__(256, 3)
void gemm3_fused(const unsigned char* __restrict__ A,   // h2 [B,1024] fp8
                 const unsigned char* __restrict__ Wt,  // W3 [128,1024] fp8
                 const float* __restrict__ bias,        // [128]
                 const float* __restrict__ eps,         // [B,64]
                 float* __restrict__ act_out, float* __restrict__ logp_out,
                 float descale, int K) {
    __shared__ char smem[32768];
    char* lA = smem;             // 64x128 B = 8 KB
    char* lB = smem + 8192;      // 128x128 B = 16 KB
    float* fmu = (float*)smem;            // epilogue 64x64 f32
    float* fls = (float*)(smem + 16384);
    const int tid  = threadIdx.x;
    const int wv   = tid >> 6, lane = tid & 63;
    const int wr   = wv >> 1,  wc   = wv & 1;     // wave: 32 rows x 64 cols
    const int l15  = lane & 15, l4  = lane >> 4;
    const size_t rowA0 = (size_t)blockIdx.x * 64;
    const unsigned char* Ab = A + rowA0 * K;
    const int qsw = ((tid & 7) ^ ((tid >> 3) & 7)) * 16;
    const int srow = tid >> 3;
    const int p0 = ((l4 * 2) ^ (l15 & 7)) * 16;
    const int p1 = ((l4 * 2 + 1) ^ (l15 & 7)) * 16;

    f32x4 acc[2][4];
    #pragma unroll
    for (int i = 0; i < 2; ++i)
        #pragma unroll
        for (int j = 0; j < 4; ++j)
            acc[i][j] = f32x4{0.f, 0.f, 0.f, 0.f};

    for (int k0 = 0; k0 < K; k0 += 128) {
        #pragma unroll
        for (int c = 0; c < 2; ++c)
            g2l16(Ab + (size_t)(c * 32 + srow) * K + k0 + qsw, lA + c * 4096 + tid * 16);
        #pragma unroll
        for (int c = 0; c < 4; ++c)
            g2l16(Wt + (size_t)(c * 32 + srow) * K + k0 + qsw, lB + c * 4096 + tid * 16);
        __syncthreads();
        union { v8i v; v4i h[2]; } af[2], bfr[4];
        #pragma unroll
        for (int i = 0; i < 2; ++i) {
            const char* ar = lA + (wr * 32 + i * 16 + l15) * 128;
            af[i].h[0] = *(const v4i*)(ar + p0);
            af[i].h[1] = *(const v4i*)(ar + p1);
        }
        #pragma unroll
        for (int j = 0; j < 4; ++j) {
            const char* br = lB + (wc * 64 + j * 16 + l15) * 128;
            bfr[j].h[0] = *(const v4i*)(br + p0);
            bfr[j].h[1] = *(const v4i*)(br + p1);
        }
        #pragma unroll
        for (int i = 0; i < 2; ++i)
            #pragma unroll
            for (int j = 0; j < 4; ++j)
                acc[i][j] = __builtin_amdgcn_mfma_scale_f32_16x16x128_f8f6f4(
                    af[i].v, bfr[j].v, acc[i][j], 0, 0, 0, 0x7F7F7F7F, 0, 0x7F7F7F7F);
        __syncthreads();
    }

    // Epilogue: cols 0..63 = mu (wc=0), 64..127 = log_std (wc=1); +row rotation in LDS
    {
        float* dst = wc ? fls : fmu;
        #pragma unroll
        for (int i = 0; i < 2; ++i) {
            #pragma unroll
            for (int j = 0; j < 4; ++j) {
                int c = j * 16 + l15;                 // 0..63
                float bv = bias[wc * 64 + c];
                #pragma unroll
                for (int r = 0; r < 4; ++r) {
                    int lr = wr * 32 + i * 16 + l4 * 4 + r;   // 0..63
                    dst[lr * 64 + ((c + lr) & 63)] = acc[i][j][r] * descale + bv;
                }
            }
        }
    }
    __syncthreads();
    {
        int r = tid >> 2;                              // 0..63
        size_t grow = rowA0 + r;
        float lp = 0.f;
        #pragma unroll
        for (int t = 0; t < 4; ++t) {
            int j0 = (tid & 3) * 16 + t * 4;           // float4-aligned col chunk
            float4 e4 = *(const float4*)(eps + grow * 64 + j0);
            float ee[4] = {e4.x, e4.y, e4.z, e4.w};
            float a4[4];
            #pragma unroll
            for (int k = 0; k < 4; ++k) {
                int j = j0 + k;
                int rot = (j + r) & 63;
                float mu = fmu[r * 64 + rot];
                float ls = fls[r * 64 + rot];
                ls = fminf(fmaxf(ls, -20.f), 2.f);
                float sd = expf(ls);
                float e  = ee[k];
                float pi = fmaf(sd, e, mu);
                a4[k] = tanhf(pi);
                lp += -0.5f * e * e - ls - 0.91893853320467274178f;
                float xn = -2.f * pi;
                float sp = fmaxf(xn, 0.f) + log1pf(expf(-fabsf(xn)));
                lp -= 2.f * (0.69314718055994530942f - pi - sp);
            }
            *(float4*)(act_out + grow * 64 + j0) = make_float4(a4[0], a4[1], a4[2], a4[3]);
        }
        lp += __shfl_xor(lp, 1);
        lp += __shfl_xor(lp, 2);
        if ((tid & 3) == 0) logp_out[grow] = lp;
    }
}

// ---------- launch ----------
extern "C" void kernel_launch(void* const* d_in, const int* in_sizes, int n_in,
                              void* d_out, int out_size, void* d_ws, size_t ws_size,
                              hipStream_t stream) {
    const float* obs = (const float*)d_in[0];
    const float* eps = (const float*)d_in[1];
    const float* W1  = (const float*)d_in[2];
    const float* b1  = (const float*)d_in[3];
    const float* W2  = (const float*)d_in[4];
    const float* b2  = (const float*)d_in[5];
    const float* W3  = (const float*)d_in[6];
    const float* b3  = (const float*)d_in[7];
    const int B = 32768, OBS = 512, H1 = 1024, H2 = 1024;

    char* ws = (char*)d_ws;
    unsigned char* x8  = (unsigned char*)(ws);               // 16 MB [B*512]
    unsigned char* h1  = (unsigned char*)(ws + 16777216);    // 32 MB
    unsigned char* h2  = (unsigned char*)(ws + 50331648);    // 32 MB
    unsigned char* W1s = (unsigned char*)(ws + 83886080);    // 512 KB
    unsigned char* W2s = (unsigned char*)(ws + 84410368);    // 1 MB
    unsigned char* W3s = (unsigned char*)(ws + 85458944);    // 128 KB
    float*         b1q = (float*)(ws + 85590016);
    float*         b2q = (float*)(ws + 85594112);
    float*         b3q = (float*)(ws + 85598208);
    float*         pmax = (float*)(ws + 85598720);           // 288 floats

    prep_cvt<<<8480, 256, 0, stream>>>(W1, W2, W3, pmax, obs, x8);
    quant_all<<<833, 256, 0, stream>>>(W1, W2, W3, b1, b2, b3,
                                       W1s, W2s, W3s, b1q, b2q, b3q, pmax);

    // scale bookkeeping (all powers of 2, exact):
    //   W* stored *2^10 ; x stored *1 (s_in^2 folded into descale1)
    //   h1 stored *2^24 ; h2 stored *2^22
    const float desc1 = (float)((1.0 / 12000.0) * (1.0 / 12000.0) / 1024.0);
    const float osc1  = 16777216.f;                   // 2^24
    const float desc2 = 1.0f / 17179869184.f;         // 2^-34
    const float osc2  = 4194304.f;                    // 2^22
    const float desc3 = (float)(1.0 / 4294967296.0);  // 2^-32

    gemm8<3><<<dim3(8, 128), 256, 0, stream>>>(x8, W1s, b1q, h1, desc1, osc1, H1, OBS);
    gemm8<3><<<dim3(8, 128), 256, 0, stream>>>(h1, W2s, b2q, h2, desc2, osc2, H2, H1);

    float* act_out  = (float*)d_out;
    float* logp_out = act_out + (size_t)B * 64;
    gemm3_fused<<<512, 256, 0, stream>>>(h2, W3s, b3q, eps, act_out, logp_out, desc3, H2);
}